// Round 10
// baseline (693.566 us; speedup 1.0000x reference)
//
#include <hip/hip_runtime.h>

#define N_NODES 10000
#define N_EDGES 160000
#define HID 128
#define NG 100
#define NF 64
#define NIO 4096     // NF*NF (w2 row stride)
#define NJ 8192      // permuted columns: o(64) x k(128), o-major
#define M_PAD 10240  // padded x rows (chunked GEMM may read past N_NODES)

typedef short bf16x8 __attribute__((ext_vector_type(8)));
typedef float f32x4 __attribute__((ext_vector_type(4)));

__device__ __forceinline__ unsigned short f2b(float f) {
    unsigned int u = __float_as_uint(f);
    u += 0x7fffu + ((u >> 16) & 1u);  // RNE
    return (unsigned short)(u >> 16);
}
__device__ __forceinline__ float b2f(unsigned short s) { return __uint_as_float((unsigned int)s << 16); }

// fragment-major index: element (row, k) of a K=64 operand, panel stride 1024
__device__ __forceinline__ long fidx64(int row, int k) {
    return (long)(row >> 4) * 1024 + (k >> 5) * 512 + ((((k >> 3) & 3) * 16 + (row & 15))) * 8 + (k & 7);
}
// K=128 operand, panel stride 2048
__device__ __forceinline__ long fidx128(int row, int k) {
    return (long)(row >> 4) * 2048 + (k >> 5) * 512 + ((((k >> 3) & 3) * 16 + (row & 15))) * 8 + (k & 7);
}

// ---------------- histograms: src-count and dst-count ----------------
__global__ void hist_kernel(const int* __restrict__ src, const int* __restrict__ dst,
                            int* __restrict__ cntS, int* __restrict__ cntD) {
    int e = blockIdx.x * 256 + threadIdx.x;
    if (e < N_EDGES) {
        atomicAdd(&cntS[src[e]], 1);
        atomicAdd(&cntD[dst[e]], 1);
    }
}

// ---------------- single-pass dual scan: rowptrS/rowptrD = excl-prefix; invd from cntD ----------------
#define SCAN_C 40  // 256 threads x 40 = 10240 >= N_NODES
__global__ void scan2_kernel(const int* __restrict__ cntS, const int* __restrict__ cntD,
                             int* __restrict__ rowptrS, int* __restrict__ rowptrD,
                             float* __restrict__ invd) {
    __shared__ int wsum[4];
    int t = threadIdx.x, wv = t >> 6, l = t & 63;
    int base_i = t * SCAN_C;
    for (int which = 0; which < 2; ++which) {
        const int* cnt = which ? cntD : cntS;
        int* rowptr = which ? rowptrD : rowptrS;
        int loc[SCAN_C];
        int sum = 0;
#pragma unroll
        for (int j = 0; j < SCAN_C; ++j) {
            int g = base_i + j;
            int v = (g < N_NODES) ? cnt[g] : 0;
            loc[j] = sum;
            sum += v;
        }
        int incl = sum;
        for (int off = 1; off < 64; off <<= 1) {
            int v = __shfl_up(incl, off);
            if (l >= off) incl += v;
        }
        if (l == 63) wsum[wv] = incl;
        __syncthreads();
        int wbase = 0;
#pragma unroll
        for (int w = 0; w < 4; ++w) wbase += (w < wv) ? wsum[w] : 0;
        int tbase = wbase + incl - sum;
#pragma unroll
        for (int j = 0; j < SCAN_C; ++j) {
            int g = base_i + j;
            if (g <= N_NODES) rowptr[g] = tbase + loc[j];
            if (which == 1 && g < N_NODES) invd[g] = 1.0f / fmaxf((float)cnt[g], 1.0f);
        }
        __syncthreads();  // protect wsum reuse across passes
    }
}

// ---------------- scatter: edgeOf[rankS], srcRank[rankD] ----------------
__global__ void scatter_kernel(const int* __restrict__ src, const int* __restrict__ dst,
                               const int* __restrict__ rowptrS, const int* __restrict__ rowptrD,
                               int* __restrict__ fillS, int* __restrict__ fillD,
                               int* __restrict__ edgeOf, int* __restrict__ srcRank) {
    int e = blockIdx.x * 256 + threadIdx.x;
    if (e < N_EDGES) {
        int s = src[e], d = dst[e];
        int rS = rowptrS[s] + atomicAdd(&fillS[s], 1);
        int rD = rowptrD[d] + atomicAdd(&fillD[d], 1);
        edgeOf[rS] = e;
        srcRank[rD] = rS;
    }
}

// ---------------- x0 = relu(h @ lin0_w + b); f32 + xh mirror + fused xb2 ----------------
__global__ void lin0_kernel(const float* __restrict__ h, const float* __restrict__ w,
                            const float* __restrict__ b, const float* __restrict__ b2,
                            float* __restrict__ x, unsigned short* __restrict__ xh,
                            float* __restrict__ xb2) {
    int wv = threadIdx.x >> 6, l = threadIdx.x & 63;
    int n = blockIdx.x * 4 + wv;
    float h0 = h[n * HID + l];
    float h1 = h[n * HID + 64 + l];
    float acc = b[l];
#pragma unroll
    for (int i = 0; i < 64; ++i) {
        acc += __shfl(h0, i) * w[i * NF + l];
        acc += __shfl(h1, i) * w[(64 + i) * NF + l];
    }
    float v = fmaxf(acc, 0.0f);
    x[n * NF + l] = v;
    xh[fidx64(n, l)] = f2b(v);
    float xb = 0.0f;
#pragma unroll
    for (int i = 0; i < 64; ++i) xb += __shfl(v, i) * b2[i * 64 + l];
    xb2[n * NF + l] = xb;
}

// ---------------- eaperm: ea rows -> rank order, split-bf16, fragment-major (K pad 128) ----------------
__global__ void eaperm_kernel(const float* __restrict__ ea, const int* __restrict__ edgeOf,
                              unsigned short* __restrict__ eah, unsigned short* __restrict__ eal) {
    int t = threadIdx.x;
    int r15 = t & 15, ksl = t >> 4;
    int ks = ksl >> 2, lk = ksl & 3;
    long rank = (long)blockIdx.x * 16 + r15;
    long e = edgeOf[rank];
    int c0 = ks * 32 + lk * 8;
    unsigned int uh[4], ul[4];
#pragma unroll
    for (int p = 0; p < 4; ++p) {
        float v0 = (c0 + 2 * p < NG) ? ea[e * NG + c0 + 2 * p] : 0.0f;
        float v1 = (c0 + 2 * p + 1 < NG) ? ea[e * NG + c0 + 2 * p + 1] : 0.0f;
        unsigned short h0 = f2b(v0), h1 = f2b(v1);
        uh[p] = ((unsigned int)h1 << 16) | h0;
        unsigned short l0 = f2b(v0 - b2f(h0)), l1 = f2b(v1 - b2f(h1));
        ul[p] = ((unsigned int)l1 << 16) | l0;
    }
    long idx = (long)blockIdx.x * 2048 + ks * 512 + (lk * 16 + r15) * 8;
    *(uint4*)(eah + idx) = make_uint4(uh[0], uh[1], uh[2], uh[3]);
    *(uint4*)(eal + idx) = make_uint4(ul[0], ul[1], ul[2], ul[3]);
}

// ---------------- merged weight permute: w1 split (first 16384 ids) + w2 single-bf16 ----------------
__global__ void wpt_kernel(const float* __restrict__ w1, const float* __restrict__ w2,
                           unsigned short* __restrict__ w1h, unsigned short* __restrict__ w1l,
                           unsigned short* __restrict__ w2h) {
    int id = blockIdx.x * 256 + threadIdx.x;
    if (id < HID * HID) {  // w1: k = id&127, c = id>>7
        int k = id & 127, c = id >> 7;
        float v = (k < NG) ? w1[k * HID + c] : 0.0f;
        unsigned short hi = f2b(v);
        long idx = fidx128(c, k);
        w1h[idx] = hi;
        w1l[idx] = f2b(v - b2f(hi));
    } else {
        int id2 = id - HID * HID;  // id2 = j*64 + i
        int i = id2 & 63, j = id2 >> 6;
        int o = j >> 7, k = j & 127;  // j = o*128 + k
        w2h[fidx64(j, i)] = f2b(w2[k * NIO + i * 64 + o]);
    }
}

// ---------------- hgemm: hidp = relu(eap @ w1 + b1), split 3-pass (unchanged) ----------------
__launch_bounds__(256)
__global__ void hgemm_kernel(const unsigned short* __restrict__ eah, const unsigned short* __restrict__ eal,
                             const unsigned short* __restrict__ w1h, const unsigned short* __restrict__ w1l,
                             const float* __restrict__ b1, unsigned short* __restrict__ hidp) {
    __shared__ float stg[4][1056];
    const int tid = threadIdx.x, wv = tid >> 6, l = tid & 63;
    const long grow = (long)blockIdx.x * 128;
    const int wr = (wv >> 1) * 64, wc = (wv & 1) * 64;
    const long apan0 = (grow >> 4) + (wr >> 4);
    const long bpan0 = (wc >> 4);

    f32x4 acc[4][4] = {};
#pragma unroll
    for (int ks = 0; ks < 4; ++ks) {
        bf16x8 ah[4], al[4], bh[4], bl[4];
#pragma unroll
        for (int m = 0; m < 4; ++m) {
            long o = (apan0 + m) * 2048 + ks * 512 + (long)l * 8;
            ah[m] = *(const bf16x8*)(eah + o);
            al[m] = *(const bf16x8*)(eal + o);
        }
#pragma unroll
        for (int n = 0; n < 4; ++n) {
            long o = (bpan0 + n) * 2048 + ks * 512 + (long)l * 8;
            bh[n] = *(const bf16x8*)(w1h + o);
            bl[n] = *(const bf16x8*)(w1l + o);
        }
#pragma unroll
        for (int m = 0; m < 4; ++m)
#pragma unroll
            for (int n = 0; n < 4; ++n) {
                acc[m][n] = __builtin_amdgcn_mfma_f32_16x16x32_bf16(ah[m], bh[n], acc[m][n], 0, 0, 0);
                acc[m][n] = __builtin_amdgcn_mfma_f32_16x16x32_bf16(ah[m], bl[n], acc[m][n], 0, 0, 0);
                acc[m][n] = __builtin_amdgcn_mfma_f32_16x16x32_bf16(al[m], bh[n], acc[m][n], 0, 0, 0);
            }
    }

    float* s = stg[wv];
    int r8 = l >> 3, cg = l & 7;
#pragma unroll
    for (int m = 0; m < 4; ++m) {
#pragma unroll
        for (int n = 0; n < 4; ++n)
#pragma unroll
            for (int q = 0; q < 4; ++q)
                s[((l >> 4) * 4 + q) * 66 + n * 16 + (l & 15)] = acc[m][n][q];
#pragma unroll
        for (int it = 0; it < 2; ++it) {
            int row = it * 8 + r8;
            const float* sr = s + row * 66 + cg * 8;
            int colbase = wc + cg * 8;
            unsigned int u[4];
#pragma unroll
            for (int p = 0; p < 4; ++p) {
                float f0 = fmaxf(sr[2 * p] + b1[colbase + 2 * p], 0.0f);
                float f1 = fmaxf(sr[2 * p + 1] + b1[colbase + 2 * p + 1], 0.0f);
                u[p] = ((unsigned int)f2b(f1) << 16) | f2b(f0);
            }
            long R = grow + wr + m * 16 + row;
            *(uint4*)(hidp + R * HID + colbase) = make_uint4(u[0], u[1], u[2], u[3]);
        }
    }
}

// ---------------- ygemm: single-pass bf16 (xh, w2h only) ----------------
__launch_bounds__(256)
__global__ void ygemm_kernel(const unsigned short* __restrict__ xh,
                             const unsigned short* __restrict__ wh,
                             unsigned short* __restrict__ y, int n0) {
    __shared__ float stg[4][1056];
    const int tid = threadIdx.x, wv = tid >> 6, l = tid & 63;
    const int grow = blockIdx.x * 128;
    const int col0 = blockIdx.y * 128;
    const int wr = (wv >> 1) * 64, wc = (wv & 1) * 64;
    const long apan0 = ((n0 + grow + wr) >> 4);
    const long bpan0 = ((col0 + wc) >> 4);

    f32x4 acc[4][4] = {};
#pragma unroll
    for (int ks = 0; ks < 2; ++ks) {
        bf16x8 a[4], b[4];
#pragma unroll
        for (int m = 0; m < 4; ++m)
            a[m] = *(const bf16x8*)(xh + (apan0 + m) * 1024 + ks * 512 + (long)l * 8);
#pragma unroll
        for (int n = 0; n < 4; ++n)
            b[n] = *(const bf16x8*)(wh + (bpan0 + n) * 1024 + ks * 512 + (long)l * 8);
#pragma unroll
        for (int m = 0; m < 4; ++m)
#pragma unroll
            for (int n = 0; n < 4; ++n)
                acc[m][n] = __builtin_amdgcn_mfma_f32_16x16x32_bf16(a[m], b[n], acc[m][n], 0, 0, 0);
    }

    float* s = stg[wv];
    int r8 = l >> 3, cg = l & 7;
#pragma unroll
    for (int m = 0; m < 4; ++m) {
#pragma unroll
        for (int n = 0; n < 4; ++n)
#pragma unroll
            for (int q = 0; q < 4; ++q)
                s[((l >> 4) * 4 + q) * 66 + n * 16 + (l & 15)] = acc[m][n][q];
#pragma unroll
        for (int it = 0; it < 2; ++it) {
            int row = it * 8 + r8;
            const float* sr = s + row * 66 + cg * 8;
            unsigned int u[4];
#pragma unroll
            for (int p = 0; p < 4; ++p)
                u[p] = ((unsigned int)f2b(sr[2 * p + 1]) << 16) | f2b(sr[2 * p]);
            long R = grow + wr + m * 16 + row;
            *(uint4*)(y + R * NJ + col0 + wc + cg * 8) = make_uint4(u[0], u[1], u[2], u[3]);
        }
    }
}

// ---------------- per-node MFMA matvec -> plain msg stores (no atomics) ----------------
__global__ void matvec_mfma_kernel(const unsigned short* __restrict__ y,
                                   const unsigned short* __restrict__ hidp,
                                   const int* __restrict__ rowptrS,
                                   const float* __restrict__ xb2,
                                   unsigned short* __restrict__ msg, int n0) {
    int wv = threadIdx.x >> 6, l = threadIdx.x & 63;
    int s = n0 + blockIdx.x;
    int r0 = rowptrS[s], r1 = rowptrS[s + 1];
    if (r0 == r1) return;
    int co = wv * 16;
    int lc = l & 15, lk = l >> 4;

    const unsigned short* Ys = y + (long)(s - n0) * NJ + (co + lc) * HID;
    bf16x8 b[4];
#pragma unroll
    for (int ks = 0; ks < 4; ++ks) b[ks] = *(const bf16x8*)(Ys + ks * 32 + lk * 8);
    float xb2v = xb2[(long)s * NF + co + lc];

    for (int mt = r0; mt < r1; mt += 16) {
        const unsigned short* Hs = hidp + (long)(mt + lc) * HID + lk * 8;
        f32x4 acc = {};
#pragma unroll
        for (int ks = 0; ks < 4; ++ks) {
            bf16x8 a = *(const bf16x8*)(Hs + ks * 32);  // rows beyond r1: pad garbage, discarded
            acc = __builtin_amdgcn_mfma_f32_16x16x32_bf16(a, b[ks], acc, 0, 0, 0);
        }
#pragma unroll
        for (int q = 0; q < 4; ++q) {
            int rank = mt + lk * 4 + q;
            if (rank < r1) msg[(long)rank * NF + co + lc] = f2b(acc[q] + xb2v);
        }
    }
}

// ---------------- combine: dst-CSR gather of msg + root GEMM + bias ----------------
__global__ void combine_kernel(const float* __restrict__ x, const unsigned short* __restrict__ msg,
                               const int* __restrict__ srcRank, const int* __restrict__ rowptrD,
                               const float* __restrict__ invd, const float* __restrict__ rw,
                               const float* __restrict__ cb, const float* __restrict__ b2,
                               float* __restrict__ xo, unsigned short* __restrict__ xh,
                               float* __restrict__ xb2) {
    int wv = threadIdx.x >> 6, l = threadIdx.x & 63;
    int n = blockIdx.x * 4 + wv;
    float xv = x[n * NF + l];
    float acc = cb[l];
#pragma unroll
    for (int i = 0; i < 64; ++i) acc += __shfl(xv, i) * rw[i * NF + l];
    float sum = 0.0f;
    int r0 = rowptrD[n], r1 = rowptrD[n + 1];
    for (int r = r0; r < r1; ++r) {
        int rS = srcRank[r];
        sum += b2f(msg[(long)rS * NF + l]);  // 128B coalesced row per edge
    }
    float v = sum * invd[n] + acc;
    xo[n * NF + l] = v;
    if (xh) {
        xh[fidx64(n, l)] = f2b(v);
        float xb = 0.0f;
#pragma unroll
        for (int i = 0; i < 64; ++i) xb += __shfl(v, i) * b2[i * 64 + l];
        xb2[n * NF + l] = xb;
    }
}

extern "C" void kernel_launch(void* const* d_in, const int* in_sizes, int n_in,
                              void* d_out, int out_size, void* d_ws, size_t ws_size,
                              hipStream_t stream) {
    const float* h = (const float*)d_in[0];
    const int* ei = (const int*)d_in[1];
    const float* ea = (const float*)d_in[3];
    const float* lin0_w = (const float*)d_in[5];
    const float* lin0_b = (const float*)d_in[6];
    const float* nn_w1 = (const float*)d_in[7];
    const float* nn_b1 = (const float*)d_in[8];
    const float* nn_w2 = (const float*)d_in[9];
    const float* nn_b2 = (const float*)d_in[10];
    const float* root_w = (const float*)d_in[11];
    const float* conv_b = (const float*)d_in[12];
    const int* srcIdx = ei;
    const int* dstIdx = ei + N_EDGES;

    // ---- tier selection ----
    const size_t eaBytes = (size_t)2 * N_EDGES * HID * 2;  // eah+eal (aliased with y region)
    const size_t fixed =
        (size_t)N_EDGES * NF * 2 +          // msg (bf16)
        (size_t)(N_EDGES + 16) * HID * 2 +  // hidp
        (size_t)NJ * NF * 2 +               // w2h
        (size_t)HID * HID * 2 * 2 +         // w1 hi/lo
        (size_t)M_PAD * NF * 2 +            // xh mirror
        (size_t)N_NODES * NF * 4 * 3 +      // xA, xB, xb2
        4 * 40192 +                         // cnt/fill block
        (size_t)(N_NODES + 1) * 4 * 2 +     // rowptrS, rowptrD
        (size_t)N_EDGES * 4 * 2 +           // edgeOf, srcRank
        32768;
    int nc = 0, CSn = 0;
    size_t region_bytes = 0;
    for (int c = 1; c <= 16; c *= 2) {
        int csn = (((N_NODES + c - 1) / c) + 127) & ~127;
        size_t rb = (size_t)csn * NJ * 2;
        if (rb < eaBytes) rb = eaBytes;
        if (fixed + rb <= ws_size) { nc = c; CSn = csn; region_bytes = rb; break; }
    }
    if (nc == 0) {
        hipMemsetAsync(d_out, 0, (size_t)out_size * 4, stream);
        return;
    }

    char* ws = (char*)d_ws;
    size_t off = 0;
    auto alloc = [&](size_t bytes) {
        char* p = ws + off;
        off += (bytes + 255) & ~(size_t)255;
        return p;
    };
    unsigned short* region = (unsigned short*)alloc(region_bytes);
    unsigned short* y = region;
    unsigned short* eah = region;
    unsigned short* eal = region + (size_t)N_EDGES * HID;
    unsigned short* msg = (unsigned short*)alloc((size_t)N_EDGES * NF * 2);
    unsigned short* hidp = (unsigned short*)alloc((size_t)(N_EDGES + 16) * HID * 2);
    unsigned short* w2h = (unsigned short*)alloc((size_t)NJ * NF * 2);
    unsigned short* w1h = (unsigned short*)alloc((size_t)HID * HID * 2);
    unsigned short* w1l = (unsigned short*)alloc((size_t)HID * HID * 2);
    unsigned short* xh = (unsigned short*)alloc((size_t)M_PAD * NF * 2);
    float* xA = (float*)alloc((size_t)N_NODES * NF * 4);
    float* xB = (float*)alloc((size_t)N_NODES * NF * 4);
    float* xb2 = (float*)alloc((size_t)N_NODES * NF * 4);
    char* cntblk = alloc(4 * 40192);  // cntS | cntD | fillS | fillD
    int* cntS = (int*)cntblk;
    int* cntD = (int*)(cntblk + 40192);
    int* fillS = (int*)(cntblk + 2 * 40192);
    int* fillD = (int*)(cntblk + 3 * 40192);
    float* invd = (float*)alloc((size_t)N_NODES * 4);
    int* rowptrS = (int*)alloc((size_t)(N_NODES + 1) * 4);
    int* rowptrD = (int*)alloc((size_t)(N_NODES + 1) * 4);
    int* edgeOf = (int*)alloc((size_t)N_EDGES * 4);
    int* srcRank = (int*)alloc((size_t)N_EDGES * 4);

    // ---- prep: dual CSR + features + weights + hidden ----
    hipMemsetAsync(cntblk, 0, 4 * 40192, stream);
    hist_kernel<<<(N_EDGES + 255) / 256, 256, 0, stream>>>(srcIdx, dstIdx, cntS, cntD);
    scan2_kernel<<<1, 256, 0, stream>>>(cntS, cntD, rowptrS, rowptrD, invd);
    scatter_kernel<<<(N_EDGES + 255) / 256, 256, 0, stream>>>(srcIdx, dstIdx, rowptrS, rowptrD,
                                                              fillS, fillD, edgeOf, srcRank);
    lin0_kernel<<<N_NODES / 4, 256, 0, stream>>>(h, lin0_w, lin0_b, nn_b2, xA, xh, xb2);
    eaperm_kernel<<<N_EDGES / 16, 256, 0, stream>>>(ea, edgeOf, eah, eal);
    wpt_kernel<<<(HID * HID + NJ * NF) / 256, 256, 0, stream>>>(nn_w1, nn_w2, w1h, w1l, w2h);
    hgemm_kernel<<<N_EDGES / 128, 256, 0, stream>>>(eah, eal, w1h, w1l, nn_b1, hidp);  // consumes ea region

    // ---- two conv applications (shared weights) ----
    for (int conv = 0; conv < 2; ++conv) {
        const float* xin = conv ? xB : xA;
        float* xout = conv ? (float*)d_out : xB;
        unsigned short* mh = conv ? nullptr : xh;

        for (int c = 0; c < nc; ++c) {
            int n0 = c * CSn;
            int n1 = n0 + CSn; if (n1 > N_NODES) n1 = N_NODES;
            if (n0 >= N_NODES) break;
            int gx = (n1 - n0 + 127) / 128;
            ygemm_kernel<<<dim3(gx, NJ / 128), 256, 0, stream>>>(xh, w2h, y, n0);
            matvec_mfma_kernel<<<n1 - n0, 256, 0, stream>>>(y, hidp, rowptrS, xb2, msg, n0);
        }
        combine_kernel<<<N_NODES / 4, 256, 0, stream>>>(xin, msg, srcRank, rowptrD, invd,
                                                        root_w, conv_b, nn_b2, xout, mh, xb2);
    }
}

// Round 11
// 671.182 us; speedup vs baseline: 1.0334x; 1.0334x over previous
//
#include <hip/hip_runtime.h>

#define N_NODES 10000
#define N_EDGES 160000
#define HID 128
#define NG 100
#define NF 64
#define NIO 4096     // NF*NF (w2 row stride)
#define NJ 8192      // permuted columns: o(64) x k(128), o-major
#define M_PAD 10240  // padded x rows (chunked GEMM may read past N_NODES)

typedef short bf16x8 __attribute__((ext_vector_type(8)));
typedef float f32x4 __attribute__((ext_vector_type(4)));

__device__ __forceinline__ unsigned short f2b(float f) {
    unsigned int u = __float_as_uint(f);
    u += 0x7fffu + ((u >> 16) & 1u);  // RNE
    return (unsigned short)(u >> 16);
}
__device__ __forceinline__ float b2f(unsigned short s) { return __uint_as_float((unsigned int)s << 16); }

// fragment-major index: element (row, k) of a K=64 operand, panel stride 1024
__device__ __forceinline__ long fidx64(int row, int k) {
    return (long)(row >> 4) * 1024 + (k >> 5) * 512 + ((((k >> 3) & 3) * 16 + (row & 15))) * 8 + (k & 7);
}
// K=128 operand, panel stride 2048
__device__ __forceinline__ long fidx128(int row, int k) {
    return (long)(row >> 4) * 2048 + (k >> 5) * 512 + ((((k >> 3) & 3) * 16 + (row & 15))) * 8 + (k & 7);
}

// ---------------- histograms: src-count and dst-count ----------------
__global__ void hist_kernel(const int* __restrict__ src, const int* __restrict__ dst,
                            int* __restrict__ cntS, int* __restrict__ cntD) {
    int e = blockIdx.x * 256 + threadIdx.x;
    if (e < N_EDGES) {
        atomicAdd(&cntS[src[e]], 1);
        atomicAdd(&cntD[dst[e]], 1);
    }
}

// ---------------- single-pass dual scan: rowptrS/rowptrD = excl-prefix; invd from cntD ----------------
#define SCAN_C 40  // 256 threads x 40 = 10240 >= N_NODES
__global__ void scan2_kernel(const int* __restrict__ cntS, const int* __restrict__ cntD,
                             int* __restrict__ rowptrS, int* __restrict__ rowptrD,
                             float* __restrict__ invd) {
    __shared__ int wsum[4];
    int t = threadIdx.x, wv = t >> 6, l = t & 63;
    int base_i = t * SCAN_C;
    for (int which = 0; which < 2; ++which) {
        const int* cnt = which ? cntD : cntS;
        int* rowptr = which ? rowptrD : rowptrS;
        int loc[SCAN_C];
        int sum = 0;
#pragma unroll
        for (int j = 0; j < SCAN_C; ++j) {
            int g = base_i + j;
            int v = (g < N_NODES) ? cnt[g] : 0;
            loc[j] = sum;
            sum += v;
        }
        int incl = sum;
        for (int off = 1; off < 64; off <<= 1) {
            int v = __shfl_up(incl, off);
            if (l >= off) incl += v;
        }
        if (l == 63) wsum[wv] = incl;
        __syncthreads();
        int wbase = 0;
#pragma unroll
        for (int w = 0; w < 4; ++w) wbase += (w < wv) ? wsum[w] : 0;
        int tbase = wbase + incl - sum;
#pragma unroll
        for (int j = 0; j < SCAN_C; ++j) {
            int g = base_i + j;
            if (g <= N_NODES) rowptr[g] = tbase + loc[j];
            if (which == 1 && g < N_NODES) invd[g] = 1.0f / fmaxf((float)cnt[g], 1.0f);
        }
        __syncthreads();  // protect wsum reuse across passes
    }
}

// ---------------- scatter: edgeOf[rankS], dstRank[rankS] ----------------
__global__ void scatter_kernel(const int* __restrict__ src, const int* __restrict__ dst,
                               const int* __restrict__ rowptrS, const int* __restrict__ rowptrD,
                               int* __restrict__ fillS, int* __restrict__ fillD,
                               int* __restrict__ edgeOf, int* __restrict__ dstRank) {
    int e = blockIdx.x * 256 + threadIdx.x;
    if (e < N_EDGES) {
        int s = src[e], d = dst[e];
        int rS = rowptrS[s] + atomicAdd(&fillS[s], 1);
        int rD = rowptrD[d] + atomicAdd(&fillD[d], 1);
        edgeOf[rS] = e;
        dstRank[rS] = rD;  // write-side permutation: src-order -> dst-slot
    }
}

// ---------------- x0 = relu(h @ lin0_w + b); f32 + xh mirror + fused xb2 ----------------
__global__ void lin0_kernel(const float* __restrict__ h, const float* __restrict__ w,
                            const float* __restrict__ b, const float* __restrict__ b2,
                            float* __restrict__ x, unsigned short* __restrict__ xh,
                            float* __restrict__ xb2) {
    int wv = threadIdx.x >> 6, l = threadIdx.x & 63;
    int n = blockIdx.x * 4 + wv;
    float h0 = h[n * HID + l];
    float h1 = h[n * HID + 64 + l];
    float acc = b[l];
#pragma unroll
    for (int i = 0; i < 64; ++i) {
        acc += __shfl(h0, i) * w[i * NF + l];
        acc += __shfl(h1, i) * w[(64 + i) * NF + l];
    }
    float v = fmaxf(acc, 0.0f);
    x[n * NF + l] = v;
    xh[fidx64(n, l)] = f2b(v);
    float xb = 0.0f;
#pragma unroll
    for (int i = 0; i < 64; ++i) xb += __shfl(v, i) * b2[i * 64 + l];
    xb2[n * NF + l] = xb;
}

// ---------------- eaperm: ea rows -> rank order, split-bf16, fragment-major (K pad 128) ----------------
__global__ void eaperm_kernel(const float* __restrict__ ea, const int* __restrict__ edgeOf,
                              unsigned short* __restrict__ eah, unsigned short* __restrict__ eal) {
    int t = threadIdx.x;
    int r15 = t & 15, ksl = t >> 4;
    int ks = ksl >> 2, lk = ksl & 3;
    long rank = (long)blockIdx.x * 16 + r15;
    long e = edgeOf[rank];
    int c0 = ks * 32 + lk * 8;
    unsigned int uh[4], ul[4];
#pragma unroll
    for (int p = 0; p < 4; ++p) {
        float v0 = (c0 + 2 * p < NG) ? ea[e * NG + c0 + 2 * p] : 0.0f;
        float v1 = (c0 + 2 * p + 1 < NG) ? ea[e * NG + c0 + 2 * p + 1] : 0.0f;
        unsigned short h0 = f2b(v0), h1 = f2b(v1);
        uh[p] = ((unsigned int)h1 << 16) | h0;
        unsigned short l0 = f2b(v0 - b2f(h0)), l1 = f2b(v1 - b2f(h1));
        ul[p] = ((unsigned int)l1 << 16) | l0;
    }
    long idx = (long)blockIdx.x * 2048 + ks * 512 + (lk * 16 + r15) * 8;
    *(uint4*)(eah + idx) = make_uint4(uh[0], uh[1], uh[2], uh[3]);
    *(uint4*)(eal + idx) = make_uint4(ul[0], ul[1], ul[2], ul[3]);
}

// ---------------- merged weight permute: w1 split (first 16384 ids) + w2 single-bf16 ----------------
__global__ void wpt_kernel(const float* __restrict__ w1, const float* __restrict__ w2,
                           unsigned short* __restrict__ w1h, unsigned short* __restrict__ w1l,
                           unsigned short* __restrict__ w2h) {
    int id = blockIdx.x * 256 + threadIdx.x;
    if (id < HID * HID) {  // w1: k = id&127, c = id>>7
        int k = id & 127, c = id >> 7;
        float v = (k < NG) ? w1[k * HID + c] : 0.0f;
        unsigned short hi = f2b(v);
        long idx = fidx128(c, k);
        w1h[idx] = hi;
        w1l[idx] = f2b(v - b2f(hi));
    } else {
        int id2 = id - HID * HID;  // id2 = j*64 + i
        int i = id2 & 63, j = id2 >> 6;
        int o = j >> 7, k = j & 127;  // j = o*128 + k
        w2h[fidx64(j, i)] = f2b(w2[k * NIO + i * 64 + o]);
    }
}

// ---------------- hgemm: hidp = relu(eap @ w1 + b1), split 3-pass ----------------
__launch_bounds__(256)
__global__ void hgemm_kernel(const unsigned short* __restrict__ eah, const unsigned short* __restrict__ eal,
                             const unsigned short* __restrict__ w1h, const unsigned short* __restrict__ w1l,
                             const float* __restrict__ b1, unsigned short* __restrict__ hidp) {
    __shared__ float stg[4][1056];
    const int tid = threadIdx.x, wv = tid >> 6, l = tid & 63;
    const long grow = (long)blockIdx.x * 128;
    const int wr = (wv >> 1) * 64, wc = (wv & 1) * 64;
    const long apan0 = (grow >> 4) + (wr >> 4);
    const long bpan0 = (wc >> 4);

    f32x4 acc[4][4] = {};
#pragma unroll
    for (int ks = 0; ks < 4; ++ks) {
        bf16x8 ah[4], al[4], bh[4], bl[4];
#pragma unroll
        for (int m = 0; m < 4; ++m) {
            long o = (apan0 + m) * 2048 + ks * 512 + (long)l * 8;
            ah[m] = *(const bf16x8*)(eah + o);
            al[m] = *(const bf16x8*)(eal + o);
        }
#pragma unroll
        for (int n = 0; n < 4; ++n) {
            long o = (bpan0 + n) * 2048 + ks * 512 + (long)l * 8;
            bh[n] = *(const bf16x8*)(w1h + o);
            bl[n] = *(const bf16x8*)(w1l + o);
        }
#pragma unroll
        for (int m = 0; m < 4; ++m)
#pragma unroll
            for (int n = 0; n < 4; ++n) {
                acc[m][n] = __builtin_amdgcn_mfma_f32_16x16x32_bf16(ah[m], bh[n], acc[m][n], 0, 0, 0);
                acc[m][n] = __builtin_amdgcn_mfma_f32_16x16x32_bf16(ah[m], bl[n], acc[m][n], 0, 0, 0);
                acc[m][n] = __builtin_amdgcn_mfma_f32_16x16x32_bf16(al[m], bh[n], acc[m][n], 0, 0, 0);
            }
    }

    float* s = stg[wv];
    int r8 = l >> 3, cg = l & 7;
#pragma unroll
    for (int m = 0; m < 4; ++m) {
#pragma unroll
        for (int n = 0; n < 4; ++n)
#pragma unroll
            for (int q = 0; q < 4; ++q)
                s[((l >> 4) * 4 + q) * 66 + n * 16 + (l & 15)] = acc[m][n][q];
#pragma unroll
        for (int it = 0; it < 2; ++it) {
            int row = it * 8 + r8;
            const float* sr = s + row * 66 + cg * 8;
            int colbase = wc + cg * 8;
            unsigned int u[4];
#pragma unroll
            for (int p = 0; p < 4; ++p) {
                float f0 = fmaxf(sr[2 * p] + b1[colbase + 2 * p], 0.0f);
                float f1 = fmaxf(sr[2 * p + 1] + b1[colbase + 2 * p + 1], 0.0f);
                u[p] = ((unsigned int)f2b(f1) << 16) | f2b(f0);
            }
            long R = grow + wr + m * 16 + row;
            *(uint4*)(hidp + R * HID + colbase) = make_uint4(u[0], u[1], u[2], u[3]);
        }
    }
}

// ---------------- ygemm: single-pass bf16 (xh, w2h only) ----------------
__launch_bounds__(256)
__global__ void ygemm_kernel(const unsigned short* __restrict__ xh,
                             const unsigned short* __restrict__ wh,
                             unsigned short* __restrict__ y, int n0) {
    __shared__ float stg[4][1056];
    const int tid = threadIdx.x, wv = tid >> 6, l = tid & 63;
    const int grow = blockIdx.x * 128;
    const int col0 = blockIdx.y * 128;
    const int wr = (wv >> 1) * 64, wc = (wv & 1) * 64;
    const long apan0 = ((n0 + grow + wr) >> 4);
    const long bpan0 = ((col0 + wc) >> 4);

    f32x4 acc[4][4] = {};
#pragma unroll
    for (int ks = 0; ks < 2; ++ks) {
        bf16x8 a[4], b[4];
#pragma unroll
        for (int m = 0; m < 4; ++m)
            a[m] = *(const bf16x8*)(xh + (apan0 + m) * 1024 + ks * 512 + (long)l * 8);
#pragma unroll
        for (int n = 0; n < 4; ++n)
            b[n] = *(const bf16x8*)(wh + (bpan0 + n) * 1024 + ks * 512 + (long)l * 8);
#pragma unroll
        for (int m = 0; m < 4; ++m)
#pragma unroll
            for (int n = 0; n < 4; ++n)
                acc[m][n] = __builtin_amdgcn_mfma_f32_16x16x32_bf16(a[m], b[n], acc[m][n], 0, 0, 0);
    }

    float* s = stg[wv];
    int r8 = l >> 3, cg = l & 7;
#pragma unroll
    for (int m = 0; m < 4; ++m) {
#pragma unroll
        for (int n = 0; n < 4; ++n)
#pragma unroll
            for (int q = 0; q < 4; ++q)
                s[((l >> 4) * 4 + q) * 66 + n * 16 + (l & 15)] = acc[m][n][q];
#pragma unroll
        for (int it = 0; it < 2; ++it) {
            int row = it * 8 + r8;
            const float* sr = s + row * 66 + cg * 8;
            unsigned int u[4];
#pragma unroll
            for (int p = 0; p < 4; ++p)
                u[p] = ((unsigned int)f2b(sr[2 * p + 1]) << 16) | f2b(sr[2 * p]);
            long R = grow + wr + m * 16 + row;
            *(uint4*)(y + R * NJ + col0 + wc + cg * 8) = make_uint4(u[0], u[1], u[2], u[3]);
        }
    }
}

// ---------------- per-node MFMA matvec -> msg stored at DST-rank slot (no atomics) ----------------
__global__ void matvec_mfma_kernel(const unsigned short* __restrict__ y,
                                   const unsigned short* __restrict__ hidp,
                                   const int* __restrict__ rowptrS, const int* __restrict__ dstRank,
                                   const float* __restrict__ xb2,
                                   unsigned short* __restrict__ msg, int n0) {
    int wv = threadIdx.x >> 6, l = threadIdx.x & 63;
    int s = n0 + blockIdx.x;
    int r0 = rowptrS[s], r1 = rowptrS[s + 1];
    if (r0 == r1) return;
    int co = wv * 16;
    int lc = l & 15, lk = l >> 4;

    const unsigned short* Ys = y + (long)(s - n0) * NJ + (co + lc) * HID;
    bf16x8 b[4];
#pragma unroll
    for (int ks = 0; ks < 4; ++ks) b[ks] = *(const bf16x8*)(Ys + ks * 32 + lk * 8);
    float xb2v = xb2[(long)s * NF + co + lc];

    for (int mt = r0; mt < r1; mt += 16) {
        const unsigned short* Hs = hidp + (long)(mt + lc) * HID + lk * 8;
        f32x4 acc = {};
#pragma unroll
        for (int ks = 0; ks < 4; ++ks) {
            bf16x8 a = *(const bf16x8*)(Hs + ks * 32);  // rows beyond r1: pad garbage, discarded
            acc = __builtin_amdgcn_mfma_f32_16x16x32_bf16(a, b[ks], acc, 0, 0, 0);
        }
#pragma unroll
        for (int q = 0; q < 4; ++q) {
            int rank = mt + lk * 4 + q;
            if (rank < r1) {
                int rD = dstRank[rank];  // scatter-write; all 4 waves cover the full 128B row
                msg[(long)rD * NF + co + lc] = f2b(acc[q] + xb2v);
            }
        }
    }
}

// ---------------- combine: CONTIGUOUS dst-rank msg sum + root GEMM + bias ----------------
__global__ void combine_kernel(const float* __restrict__ x, const unsigned short* __restrict__ msg,
                               const int* __restrict__ rowptrD,
                               const float* __restrict__ invd, const float* __restrict__ rw,
                               const float* __restrict__ cb, const float* __restrict__ b2,
                               float* __restrict__ xo, unsigned short* __restrict__ xh,
                               float* __restrict__ xb2) {
    int wv = threadIdx.x >> 6, l = threadIdx.x & 63;
    int n = blockIdx.x * 4 + wv;
    float xv = x[n * NF + l];
    float acc = cb[l];
#pragma unroll
    for (int i = 0; i < 64; ++i) acc += __shfl(xv, i) * rw[i * NF + l];
    float sum = 0.0f;
    int r0 = rowptrD[n], r1 = rowptrD[n + 1];
    for (int r = r0; r < r1; ++r)
        sum += b2f(msg[(long)r * NF + l]);  // linear stream, prefetchable
    float v = sum * invd[n] + acc;
    xo[n * NF + l] = v;
    if (xh) {
        xh[fidx64(n, l)] = f2b(v);
        float xb = 0.0f;
#pragma unroll
        for (int i = 0; i < 64; ++i) xb += __shfl(v, i) * b2[i * 64 + l];
        xb2[n * NF + l] = xb;
    }
}

extern "C" void kernel_launch(void* const* d_in, const int* in_sizes, int n_in,
                              void* d_out, int out_size, void* d_ws, size_t ws_size,
                              hipStream_t stream) {
    const float* h = (const float*)d_in[0];
    const int* ei = (const int*)d_in[1];
    const float* ea = (const float*)d_in[3];
    const float* lin0_w = (const float*)d_in[5];
    const float* lin0_b = (const float*)d_in[6];
    const float* nn_w1 = (const float*)d_in[7];
    const float* nn_b1 = (const float*)d_in[8];
    const float* nn_w2 = (const float*)d_in[9];
    const float* nn_b2 = (const float*)d_in[10];
    const float* root_w = (const float*)d_in[11];
    const float* conv_b = (const float*)d_in[12];
    const int* srcIdx = ei;
    const int* dstIdx = ei + N_EDGES;

    // ---- tier selection ----
    const size_t eaBytes = (size_t)2 * N_EDGES * HID * 2;  // eah+eal (aliased with y region)
    const size_t fixed =
        (size_t)N_EDGES * NF * 2 +          // msg (bf16, dst-rank order)
        (size_t)(N_EDGES + 16) * HID * 2 +  // hidp
        (size_t)NJ * NF * 2 +               // w2h
        (size_t)HID * HID * 2 * 2 +         // w1 hi/lo
        (size_t)M_PAD * NF * 2 +            // xh mirror
        (size_t)N_NODES * NF * 4 * 3 +      // xA, xB, xb2
        4 * 40192 +                         // cnt/fill block
        (size_t)N_NODES * 4 +               // invd
        (size_t)(N_NODES + 1) * 4 * 2 +     // rowptrS, rowptrD
        (size_t)N_EDGES * 4 * 2 +           // edgeOf, dstRank
        32768;
    int nc = 0, CSn = 0;
    size_t region_bytes = 0;
    for (int c = 1; c <= 16; c *= 2) {
        int csn = (((N_NODES + c - 1) / c) + 127) & ~127;
        size_t rb = (size_t)csn * NJ * 2;
        if (rb < eaBytes) rb = eaBytes;
        if (fixed + rb <= ws_size) { nc = c; CSn = csn; region_bytes = rb; break; }
    }
    if (nc == 0) {
        hipMemsetAsync(d_out, 0, (size_t)out_size * 4, stream);
        return;
    }

    char* ws = (char*)d_ws;
    size_t off = 0;
    auto alloc = [&](size_t bytes) {
        char* p = ws + off;
        off += (bytes + 255) & ~(size_t)255;
        return p;
    };
    unsigned short* region = (unsigned short*)alloc(region_bytes);
    unsigned short* y = region;
    unsigned short* eah = region;
    unsigned short* eal = region + (size_t)N_EDGES * HID;
    unsigned short* msg = (unsigned short*)alloc((size_t)N_EDGES * NF * 2);
    unsigned short* hidp = (unsigned short*)alloc((size_t)(N_EDGES + 16) * HID * 2);
    unsigned short* w2h = (unsigned short*)alloc((size_t)NJ * NF * 2);
    unsigned short* w1h = (unsigned short*)alloc((size_t)HID * HID * 2);
    unsigned short* w1l = (unsigned short*)alloc((size_t)HID * HID * 2);
    unsigned short* xh = (unsigned short*)alloc((size_t)M_PAD * NF * 2);
    float* xA = (float*)alloc((size_t)N_NODES * NF * 4);
    float* xB = (float*)alloc((size_t)N_NODES * NF * 4);
    float* xb2 = (float*)alloc((size_t)N_NODES * NF * 4);
    char* cntblk = alloc(4 * 40192);  // cntS | cntD | fillS | fillD
    int* cntS = (int*)cntblk;
    int* cntD = (int*)(cntblk + 40192);
    int* fillS = (int*)(cntblk + 2 * 40192);
    int* fillD = (int*)(cntblk + 3 * 40192);
    float* invd = (float*)alloc((size_t)N_NODES * 4);
    int* rowptrS = (int*)alloc((size_t)(N_NODES + 1) * 4);
    int* rowptrD = (int*)alloc((size_t)(N_NODES + 1) * 4);
    int* edgeOf = (int*)alloc((size_t)N_EDGES * 4);
    int* dstRank = (int*)alloc((size_t)N_EDGES * 4);

    // ---- prep: dual CSR + features + weights + hidden ----
    hipMemsetAsync(cntblk, 0, 4 * 40192, stream);
    hist_kernel<<<(N_EDGES + 255) / 256, 256, 0, stream>>>(srcIdx, dstIdx, cntS, cntD);
    scan2_kernel<<<1, 256, 0, stream>>>(cntS, cntD, rowptrS, rowptrD, invd);
    scatter_kernel<<<(N_EDGES + 255) / 256, 256, 0, stream>>>(srcIdx, dstIdx, rowptrS, rowptrD,
                                                              fillS, fillD, edgeOf, dstRank);
    lin0_kernel<<<N_NODES / 4, 256, 0, stream>>>(h, lin0_w, lin0_b, nn_b2, xA, xh, xb2);
    eaperm_kernel<<<N_EDGES / 16, 256, 0, stream>>>(ea, edgeOf, eah, eal);
    wpt_kernel<<<(HID * HID + NJ * NF) / 256, 256, 0, stream>>>(nn_w1, nn_w2, w1h, w1l, w2h);
    hgemm_kernel<<<N_EDGES / 128, 256, 0, stream>>>(eah, eal, w1h, w1l, nn_b1, hidp);  // consumes ea region

    // ---- two conv applications (shared weights) ----
    for (int conv = 0; conv < 2; ++conv) {
        const float* xin = conv ? xB : xA;
        float* xout = conv ? (float*)d_out : xB;
        unsigned short* mh = conv ? nullptr : xh;

        for (int c = 0; c < nc; ++c) {
            int n0 = c * CSn;
            int n1 = n0 + CSn; if (n1 > N_NODES) n1 = N_NODES;
            if (n0 >= N_NODES) break;
            int gx = (n1 - n0 + 127) / 128;
            ygemm_kernel<<<dim3(gx, NJ / 128), 256, 0, stream>>>(xh, w2h, y, n0);
            matvec_mfma_kernel<<<n1 - n0, 256, 0, stream>>>(y, hidp, rowptrS, dstRank, xb2, msg, n0);
        }
        combine_kernel<<<N_NODES / 4, 256, 0, stream>>>(xin, msg, rowptrD, invd,
                                                        root_w, conv_b, nn_b2, xout, mh, xb2);
    }
}

// Round 12
// 386.630 us; speedup vs baseline: 1.7939x; 1.7360x over previous
//
#include <hip/hip_runtime.h>

#define N_NODES 10000
#define N_EDGES 160000
#define HID 128
#define NG 100
#define NF 64
#define NIO 4096     // NF*NF (w2 row stride)
#define NJ 8192      // permuted columns: o(64) x k(128), o-major
#define M_PAD 10240  // padded x rows (chunked GEMM may read past N_NODES)

typedef short bf16x8 __attribute__((ext_vector_type(8)));
typedef float f32x4 __attribute__((ext_vector_type(4)));

__device__ __forceinline__ unsigned short f2b(float f) {
    unsigned int u = __float_as_uint(f);
    u += 0x7fffu + ((u >> 16) & 1u);  // RNE
    return (unsigned short)(u >> 16);
}
__device__ __forceinline__ float b2f(unsigned short s) { return __uint_as_float((unsigned int)s << 16); }

// fragment-major index: element (row, k) of a K=64 operand, panel stride 1024
__device__ __forceinline__ long fidx64(int row, int k) {
    return (long)(row >> 4) * 1024 + (k >> 5) * 512 + ((((k >> 3) & 3) * 16 + (row & 15))) * 8 + (k & 7);
}
// K=128 operand, panel stride 2048
__device__ __forceinline__ long fidx128(int row, int k) {
    return (long)(row >> 4) * 2048 + (k >> 5) * 512 + ((((k >> 3) & 3) * 16 + (row & 15))) * 8 + (k & 7);
}

// ---------------- histograms (dst-degree for mean; src-count for CSR) ----------------
__global__ void hist_kernel(const int* __restrict__ src, const int* __restrict__ dst,
                            float* __restrict__ deg, int* __restrict__ cnt) {
    int e = blockIdx.x * 256 + threadIdx.x;
    if (e < N_EDGES) {
        atomicAdd(&deg[dst[e]], 1.0f);
        atomicAdd(&cnt[src[e]], 1);
    }
}

// ---------------- single-pass scan: rowptr = excl-prefix(cnt); invd = 1/max(deg,1) ----------------
#define SCAN_C 40  // 256 threads x 40 = 10240 >= N_NODES
__global__ void scan_kernel(const int* __restrict__ cnt, const float* __restrict__ deg,
                            int* __restrict__ rowptr, float* __restrict__ invd) {
    __shared__ int wsum[4];
    int t = threadIdx.x, wv = t >> 6, l = t & 63;
    int base_i = t * SCAN_C;
    int loc[SCAN_C];
    int sum = 0;
#pragma unroll
    for (int j = 0; j < SCAN_C; ++j) {
        int g = base_i + j;
        int v = (g < N_NODES) ? cnt[g] : 0;
        loc[j] = sum;  // exclusive prefix within thread
        sum += v;
    }
    int incl = sum;
    for (int off = 1; off < 64; off <<= 1) {
        int v = __shfl_up(incl, off);
        if (l >= off) incl += v;
    }
    if (l == 63) wsum[wv] = incl;
    __syncthreads();
    int wbase = 0;
#pragma unroll
    for (int w = 0; w < 4; ++w) wbase += (w < wv) ? wsum[w] : 0;
    int tbase = wbase + incl - sum;  // exclusive across block
#pragma unroll
    for (int j = 0; j < SCAN_C; ++j) {
        int g = base_i + j;
        if (g <= N_NODES) rowptr[g] = tbase + loc[j];
        if (g < N_NODES) invd[g] = 1.0f / fmaxf(deg[g], 1.0f);
    }
}

// ---------------- scatter: edgeOf[rankS], dstp[rankS] ----------------
__global__ void scatter_kernel(const int* __restrict__ src, const int* __restrict__ dst,
                               const int* __restrict__ rowptr, int* __restrict__ fill,
                               int* __restrict__ edgeOf, int* __restrict__ dstp) {
    int e = blockIdx.x * 256 + threadIdx.x;
    if (e < N_EDGES) {
        int s = src[e];
        int r = rowptr[s] + atomicAdd(&fill[s], 1);
        edgeOf[r] = e;
        dstp[r] = dst[e];
    }
}

// ---------------- x0 = relu(h @ lin0_w + b); f32 + xh frag mirror + fused xb2 ----------------
__global__ void lin0_kernel(const float* __restrict__ h, const float* __restrict__ w,
                            const float* __restrict__ b, const float* __restrict__ b2,
                            float* __restrict__ x, unsigned short* __restrict__ xh,
                            float* __restrict__ xb2) {
    int wv = threadIdx.x >> 6, l = threadIdx.x & 63;
    int n = blockIdx.x * 4 + wv;
    float h0 = h[n * HID + l];
    float h1 = h[n * HID + 64 + l];
    float acc = b[l];
#pragma unroll
    for (int i = 0; i < 64; ++i) {
        acc += __shfl(h0, i) * w[i * NF + l];
        acc += __shfl(h1, i) * w[(64 + i) * NF + l];
    }
    float v = fmaxf(acc, 0.0f);
    x[n * NF + l] = v;
    xh[fidx64(n, l)] = f2b(v);
    float xb = 0.0f;
#pragma unroll
    for (int i = 0; i < 64; ++i) xb += __shfl(v, i) * b2[i * 64 + l];
    xb2[n * NF + l] = xb;
}

// ---------------- eaperm: ea rows -> rank order, split-bf16, fragment-major (K pad 128) ----------------
__global__ void eaperm_kernel(const float* __restrict__ ea, const int* __restrict__ edgeOf,
                              unsigned short* __restrict__ eah, unsigned short* __restrict__ eal) {
    int t = threadIdx.x;
    int r15 = t & 15, ksl = t >> 4;
    int ks = ksl >> 2, lk = ksl & 3;
    long rank = (long)blockIdx.x * 16 + r15;
    long e = edgeOf[rank];
    int c0 = ks * 32 + lk * 8;
    unsigned int uh[4], ul[4];
#pragma unroll
    for (int p = 0; p < 4; ++p) {
        float v0 = (c0 + 2 * p < NG) ? ea[e * NG + c0 + 2 * p] : 0.0f;
        float v1 = (c0 + 2 * p + 1 < NG) ? ea[e * NG + c0 + 2 * p + 1] : 0.0f;
        unsigned short h0 = f2b(v0), h1 = f2b(v1);
        uh[p] = ((unsigned int)h1 << 16) | h0;
        unsigned short l0 = f2b(v0 - b2f(h0)), l1 = f2b(v1 - b2f(h1));
        ul[p] = ((unsigned int)l1 << 16) | l0;
    }
    long idx = (long)blockIdx.x * 2048 + ks * 512 + (lk * 16 + r15) * 8;
    *(uint4*)(eah + idx) = make_uint4(uh[0], uh[1], uh[2], uh[3]);
    *(uint4*)(eal + idx) = make_uint4(ul[0], ul[1], ul[2], ul[3]);
}

// ---------------- merged weight permute: w1 split (first 16384 ids) + w2 single-bf16 ----------------
__global__ void wpt_kernel(const float* __restrict__ w1, const float* __restrict__ w2,
                           unsigned short* __restrict__ w1h, unsigned short* __restrict__ w1l,
                           unsigned short* __restrict__ w2h) {
    int id = blockIdx.x * 256 + threadIdx.x;
    if (id < HID * HID) {  // w1: k = id&127, c = id>>7
        int k = id & 127, c = id >> 7;
        float v = (k < NG) ? w1[k * HID + c] : 0.0f;
        unsigned short hi = f2b(v);
        long idx = fidx128(c, k);
        w1h[idx] = hi;
        w1l[idx] = f2b(v - b2f(hi));
    } else {
        int id2 = id - HID * HID;  // id2 = j*64 + i
        int i = id2 & 63, j = id2 >> 6;
        int o = j >> 7, k = j & 127;  // j = o*128 + k
        w2h[fidx64(j, i)] = f2b(w2[k * NIO + i * 64 + o]);
    }
}

// ---------------- hgemm: hidp = relu(eap @ w1 + b1), split 3-pass ----------------
__launch_bounds__(256)
__global__ void hgemm_kernel(const unsigned short* __restrict__ eah, const unsigned short* __restrict__ eal,
                             const unsigned short* __restrict__ w1h, const unsigned short* __restrict__ w1l,
                             const float* __restrict__ b1, unsigned short* __restrict__ hidp) {
    __shared__ float stg[4][1056];
    const int tid = threadIdx.x, wv = tid >> 6, l = tid & 63;
    const long grow = (long)blockIdx.x * 128;
    const int wr = (wv >> 1) * 64, wc = (wv & 1) * 64;
    const long apan0 = (grow >> 4) + (wr >> 4);
    const long bpan0 = (wc >> 4);

    f32x4 acc[4][4] = {};
#pragma unroll
    for (int ks = 0; ks < 4; ++ks) {
        bf16x8 ah[4], al[4], bh[4], bl[4];
#pragma unroll
        for (int m = 0; m < 4; ++m) {
            long o = (apan0 + m) * 2048 + ks * 512 + (long)l * 8;
            ah[m] = *(const bf16x8*)(eah + o);
            al[m] = *(const bf16x8*)(eal + o);
        }
#pragma unroll
        for (int n = 0; n < 4; ++n) {
            long o = (bpan0 + n) * 2048 + ks * 512 + (long)l * 8;
            bh[n] = *(const bf16x8*)(w1h + o);
            bl[n] = *(const bf16x8*)(w1l + o);
        }
#pragma unroll
        for (int m = 0; m < 4; ++m)
#pragma unroll
            for (int n = 0; n < 4; ++n) {
                acc[m][n] = __builtin_amdgcn_mfma_f32_16x16x32_bf16(ah[m], bh[n], acc[m][n], 0, 0, 0);
                acc[m][n] = __builtin_amdgcn_mfma_f32_16x16x32_bf16(ah[m], bl[n], acc[m][n], 0, 0, 0);
                acc[m][n] = __builtin_amdgcn_mfma_f32_16x16x32_bf16(al[m], bh[n], acc[m][n], 0, 0, 0);
            }
    }

    float* s = stg[wv];
    int r8 = l >> 3, cg = l & 7;
#pragma unroll
    for (int m = 0; m < 4; ++m) {
#pragma unroll
        for (int n = 0; n < 4; ++n)
#pragma unroll
            for (int q = 0; q < 4; ++q)
                s[((l >> 4) * 4 + q) * 66 + n * 16 + (l & 15)] = acc[m][n][q];
#pragma unroll
        for (int it = 0; it < 2; ++it) {
            int row = it * 8 + r8;
            const float* sr = s + row * 66 + cg * 8;
            int colbase = wc + cg * 8;
            unsigned int u[4];
#pragma unroll
            for (int p = 0; p < 4; ++p) {
                float f0 = fmaxf(sr[2 * p] + b1[colbase + 2 * p], 0.0f);
                float f1 = fmaxf(sr[2 * p + 1] + b1[colbase + 2 * p + 1], 0.0f);
                u[p] = ((unsigned int)f2b(f1) << 16) | f2b(f0);
            }
            long R = grow + wr + m * 16 + row;
            *(uint4*)(hidp + R * HID + colbase) = make_uint4(u[0], u[1], u[2], u[3]);
        }
    }
}

// ---------------- ygemm: single-pass bf16 (xh, w2h) — numerically validated r10/r11 ----------------
__launch_bounds__(256)
__global__ void ygemm_kernel(const unsigned short* __restrict__ xh,
                             const unsigned short* __restrict__ wh,
                             unsigned short* __restrict__ y, int n0) {
    __shared__ float stg[4][1056];
    const int tid = threadIdx.x, wv = tid >> 6, l = tid & 63;
    const int grow = blockIdx.x * 128;
    const int col0 = blockIdx.y * 128;
    const int wr = (wv >> 1) * 64, wc = (wv & 1) * 64;
    const long apan0 = ((n0 + grow + wr) >> 4);
    const long bpan0 = ((col0 + wc) >> 4);

    f32x4 acc[4][4] = {};
#pragma unroll
    for (int ks = 0; ks < 2; ++ks) {
        bf16x8 a[4], b[4];
#pragma unroll
        for (int m = 0; m < 4; ++m)
            a[m] = *(const bf16x8*)(xh + (apan0 + m) * 1024 + ks * 512 + (long)l * 8);
#pragma unroll
        for (int n = 0; n < 4; ++n)
            b[n] = *(const bf16x8*)(wh + (bpan0 + n) * 1024 + ks * 512 + (long)l * 8);
#pragma unroll
        for (int m = 0; m < 4; ++m)
#pragma unroll
            for (int n = 0; n < 4; ++n)
                acc[m][n] = __builtin_amdgcn_mfma_f32_16x16x32_bf16(a[m], b[n], acc[m][n], 0, 0, 0);
    }

    float* s = stg[wv];
    int r8 = l >> 3, cg = l & 7;
#pragma unroll
    for (int m = 0; m < 4; ++m) {
#pragma unroll
        for (int n = 0; n < 4; ++n)
#pragma unroll
            for (int q = 0; q < 4; ++q)
                s[((l >> 4) * 4 + q) * 66 + n * 16 + (l & 15)] = acc[m][n][q];
#pragma unroll
        for (int it = 0; it < 2; ++it) {
            int row = it * 8 + r8;
            const float* sr = s + row * 66 + cg * 8;
            unsigned int u[4];
#pragma unroll
            for (int p = 0; p < 4; ++p)
                u[p] = ((unsigned int)f2b(sr[2 * p + 1]) << 16) | f2b(sr[2 * p]);
            long R = grow + wr + m * 16 + row;
            *(uint4*)(y + R * NJ + col0 + wc + cg * 8) = make_uint4(u[0], u[1], u[2], u[3]);
        }
    }
}

// ---------------- per-node MFMA matvec: atomic scatter into agg (round-9 proven) ----------------
__global__ void matvec_mfma_kernel(const unsigned short* __restrict__ y,
                                   const unsigned short* __restrict__ hidp,
                                   const int* __restrict__ rowptr, const int* __restrict__ dstp,
                                   const float* __restrict__ xb2, float* __restrict__ agg,
                                   int n0) {
    int wv = threadIdx.x >> 6, l = threadIdx.x & 63;
    int s = n0 + blockIdx.x;
    int r0 = rowptr[s], r1 = rowptr[s + 1];
    if (r0 == r1) return;
    int co = wv * 16;
    int lc = l & 15, lk = l >> 4;

    const unsigned short* Ys = y + (long)(s - n0) * NJ + (co + lc) * HID;
    bf16x8 b[4];
#pragma unroll
    for (int ks = 0; ks < 4; ++ks) b[ks] = *(const bf16x8*)(Ys + ks * 32 + lk * 8);
    float xb2v = xb2[(long)s * NF + co + lc];

    for (int mt = r0; mt < r1; mt += 16) {
        const unsigned short* Hs = hidp + (long)(mt + lc) * HID + lk * 8;
        f32x4 acc = {};
#pragma unroll
        for (int ks = 0; ks < 4; ++ks) {
            bf16x8 a = *(const bf16x8*)(Hs + ks * 32);  // rows beyond r1: pad garbage, discarded
            acc = __builtin_amdgcn_mfma_f32_16x16x32_bf16(a, b[ks], acc, 0, 0, 0);
        }
#pragma unroll
        for (int q = 0; q < 4; ++q) {
            int rank = mt + lk * 4 + q;
            if (rank < r1) {
                int dd = dstp[rank];
                atomicAdd(&agg[(long)dd * NF + co + lc], acc[q] + xb2v);
            }
        }
    }
}

// ---------------- combine: agg*inv_deg + x @ root_w + conv_b (+ conv0: xh mirror & next xb2) ----------------
__global__ void combine_kernel(const float* __restrict__ x, const float* __restrict__ agg,
                               const float* __restrict__ invd, const float* __restrict__ rw,
                               const float* __restrict__ cb, const float* __restrict__ b2,
                               float* __restrict__ xo, unsigned short* __restrict__ xh,
                               float* __restrict__ xb2) {
    int wv = threadIdx.x >> 6, l = threadIdx.x & 63;
    int n = blockIdx.x * 4 + wv;
    float xv = x[n * NF + l];
    float acc = cb[l];
#pragma unroll
    for (int i = 0; i < 64; ++i) acc += __shfl(xv, i) * rw[i * NF + l];
    float v = agg[n * NF + l] * invd[n] + acc;
    xo[n * NF + l] = v;
    if (xh) {
        xh[fidx64(n, l)] = f2b(v);
        float xb = 0.0f;
#pragma unroll
        for (int i = 0; i < 64; ++i) xb += __shfl(v, i) * b2[i * 64 + l];
        xb2[n * NF + l] = xb;
    }
}

extern "C" void kernel_launch(void* const* d_in, const int* in_sizes, int n_in,
                              void* d_out, int out_size, void* d_ws, size_t ws_size,
                              hipStream_t stream) {
    const float* h = (const float*)d_in[0];
    const int* ei = (const int*)d_in[1];
    const float* ea = (const float*)d_in[3];
    const float* lin0_w = (const float*)d_in[5];
    const float* lin0_b = (const float*)d_in[6];
    const float* nn_w1 = (const float*)d_in[7];
    const float* nn_b1 = (const float*)d_in[8];
    const float* nn_w2 = (const float*)d_in[9];
    const float* nn_b2 = (const float*)d_in[10];
    const float* root_w = (const float*)d_in[11];
    const float* conv_b = (const float*)d_in[12];
    const int* srcIdx = ei;
    const int* dstIdx = ei + N_EDGES;

    // ---- tier selection ----
    const size_t eaBytes = (size_t)2 * N_EDGES * HID * 2;  // eah+eal (aliased with y region)
    const size_t fixed =
        (size_t)(N_EDGES + 16) * HID * 2 +  // hidp
        (size_t)NJ * NF * 2 +               // w2h
        (size_t)HID * HID * 2 * 2 +         // w1 hi/lo
        (size_t)M_PAD * NF * 2 +            // xh mirror
        (size_t)N_NODES * NF * 4 * 4 +      // xA, xB, agg, xb2
        3 * 40192 +                         // deg | cnt | fill block
        (size_t)N_NODES * 4 +               // invd
        (size_t)(N_NODES + 1) * 4 +         // rowptr
        (size_t)N_EDGES * 4 * 2 +           // edgeOf, dstp
        32768;
    int nc = 0, CSn = 0;
    size_t region_bytes = 0;
    for (int c = 1; c <= 16; c *= 2) {
        int csn = (((N_NODES + c - 1) / c) + 127) & ~127;
        size_t rb = (size_t)csn * NJ * 2;
        if (rb < eaBytes) rb = eaBytes;
        if (fixed + rb <= ws_size) { nc = c; CSn = csn; region_bytes = rb; break; }
    }
    if (nc == 0) {
        hipMemsetAsync(d_out, 0, (size_t)out_size * 4, stream);
        return;
    }

    char* ws = (char*)d_ws;
    size_t off = 0;
    auto alloc = [&](size_t bytes) {
        char* p = ws + off;
        off += (bytes + 255) & ~(size_t)255;
        return p;
    };
    unsigned short* region = (unsigned short*)alloc(region_bytes);
    unsigned short* y = region;
    unsigned short* eah = region;
    unsigned short* eal = region + (size_t)N_EDGES * HID;
    unsigned short* hidp = (unsigned short*)alloc((size_t)(N_EDGES + 16) * HID * 2);
    unsigned short* w2h = (unsigned short*)alloc((size_t)NJ * NF * 2);
    unsigned short* w1h = (unsigned short*)alloc((size_t)HID * HID * 2);
    unsigned short* w1l = (unsigned short*)alloc((size_t)HID * HID * 2);
    unsigned short* xh = (unsigned short*)alloc((size_t)M_PAD * NF * 2);
    float* xA = (float*)alloc((size_t)N_NODES * NF * 4);
    float* xB = (float*)alloc((size_t)N_NODES * NF * 4);
    float* agg = (float*)alloc((size_t)N_NODES * NF * 4);
    float* xb2 = (float*)alloc((size_t)N_NODES * NF * 4);
    char* degblk = alloc(3 * 40192);  // deg | cnt | fill (one memset)
    float* deg = (float*)degblk;
    int* cnt = (int*)(degblk + 40192);
    int* fill = (int*)(degblk + 2 * 40192);
    float* invd = (float*)alloc((size_t)N_NODES * 4);
    int* rowptr = (int*)alloc((size_t)(N_NODES + 1) * 4);
    int* edgeOf = (int*)alloc((size_t)N_EDGES * 4);
    int* dstp = (int*)alloc((size_t)N_EDGES * 4);

    // ---- prep: CSR by src + features + weights + hidden ----
    hipMemsetAsync(degblk, 0, 3 * 40192, stream);
    hist_kernel<<<(N_EDGES + 255) / 256, 256, 0, stream>>>(srcIdx, dstIdx, deg, cnt);
    scan_kernel<<<1, 256, 0, stream>>>(cnt, deg, rowptr, invd);
    scatter_kernel<<<(N_EDGES + 255) / 256, 256, 0, stream>>>(srcIdx, dstIdx, rowptr, fill, edgeOf, dstp);
    lin0_kernel<<<N_NODES / 4, 256, 0, stream>>>(h, lin0_w, lin0_b, nn_b2, xA, xh, xb2);
    eaperm_kernel<<<N_EDGES / 16, 256, 0, stream>>>(ea, edgeOf, eah, eal);
    wpt_kernel<<<(HID * HID + NJ * NF) / 256, 256, 0, stream>>>(nn_w1, nn_w2, w1h, w1l, w2h);
    hgemm_kernel<<<N_EDGES / 128, 256, 0, stream>>>(eah, eal, w1h, w1l, nn_b1, hidp);  // consumes ea region

    // ---- two conv applications (shared weights) ----
    for (int conv = 0; conv < 2; ++conv) {
        const float* xin = conv ? xB : xA;
        float* xout = conv ? (float*)d_out : xB;
        unsigned short* mh = conv ? nullptr : xh;

        hipMemsetAsync(agg, 0, (size_t)N_NODES * NF * 4, stream);
        for (int c = 0; c < nc; ++c) {
            int n0 = c * CSn;
            int n1 = n0 + CSn; if (n1 > N_NODES) n1 = N_NODES;
            if (n0 >= N_NODES) break;
            int gx = (n1 - n0 + 127) / 128;
            ygemm_kernel<<<dim3(gx, NJ / 128), 256, 0, stream>>>(xh, w2h, y, n0);
            matvec_mfma_kernel<<<n1 - n0, 256, 0, stream>>>(y, hidp, rowptr, dstp, xb2, agg, n0);
        }
        combine_kernel<<<N_NODES / 4, 256, 0, stream>>>(xin, agg, invd, root_w, conv_b, nn_b2,
                                                        xout, mh, xb2);
    }
}

// Round 13
// 371.462 us; speedup vs baseline: 1.8671x; 1.0408x over previous
//
#include <hip/hip_runtime.h>

#define N_NODES 10000
#define N_EDGES 160000
#define HID 128
#define NG 100
#define NF 64
#define NIO 4096     // NF*NF (w2 row stride)
#define NJ 8192      // permuted columns: o(64) x k(128), o-major
#define M_PAD 10240  // padded x rows (chunked GEMM may read past N_NODES)

typedef short bf16x8 __attribute__((ext_vector_type(8)));
typedef float f32x4 __attribute__((ext_vector_type(4)));

__device__ __forceinline__ unsigned short f2b(float f) {
    unsigned int u = __float_as_uint(f);
    u += 0x7fffu + ((u >> 16) & 1u);  // RNE
    return (unsigned short)(u >> 16);
}
__device__ __forceinline__ float b2f(unsigned short s) { return __uint_as_float((unsigned int)s << 16); }

// fragment-major index: element (row, k) of a K=64 operand, panel stride 1024
__device__ __forceinline__ long fidx64(int row, int k) {
    return (long)(row >> 4) * 1024 + (k >> 5) * 512 + ((((k >> 3) & 3) * 16 + (row & 15))) * 8 + (k & 7);
}
// K=128 operand, panel stride 2048
__device__ __forceinline__ long fidx128(int row, int k) {
    return (long)(row >> 4) * 2048 + (k >> 5) * 512 + ((((k >> 3) & 3) * 16 + (row & 15))) * 8 + (k & 7);
}

// ---------------- histograms (dst-degree for mean; src-count for CSR) ----------------
__global__ void hist_kernel(const int* __restrict__ src, const int* __restrict__ dst,
                            float* __restrict__ deg, int* __restrict__ cnt) {
    int e = blockIdx.x * 256 + threadIdx.x;
    if (e < N_EDGES) {
        atomicAdd(&deg[dst[e]], 1.0f);
        atomicAdd(&cnt[src[e]], 1);
    }
}

// ---------------- single-pass scan: rowptr = excl-prefix(cnt); invd = 1/max(deg,1) ----------------
#define SCAN_C 40  // 256 threads x 40 = 10240 >= N_NODES
__global__ void scan_kernel(const int* __restrict__ cnt, const float* __restrict__ deg,
                            int* __restrict__ rowptr, float* __restrict__ invd) {
    __shared__ int wsum[4];
    int t = threadIdx.x, wv = t >> 6, l = t & 63;
    int base_i = t * SCAN_C;
    int loc[SCAN_C];
    int sum = 0;
#pragma unroll
    for (int j = 0; j < SCAN_C; ++j) {
        int g = base_i + j;
        int v = (g < N_NODES) ? cnt[g] : 0;
        loc[j] = sum;  // exclusive prefix within thread
        sum += v;
    }
    int incl = sum;
    for (int off = 1; off < 64; off <<= 1) {
        int v = __shfl_up(incl, off);
        if (l >= off) incl += v;
    }
    if (l == 63) wsum[wv] = incl;
    __syncthreads();
    int wbase = 0;
#pragma unroll
    for (int w = 0; w < 4; ++w) wbase += (w < wv) ? wsum[w] : 0;
    int tbase = wbase + incl - sum;  // exclusive across block
#pragma unroll
    for (int j = 0; j < SCAN_C; ++j) {
        int g = base_i + j;
        if (g <= N_NODES) rowptr[g] = tbase + loc[j];
        if (g < N_NODES) invd[g] = 1.0f / fmaxf(deg[g], 1.0f);
    }
}

// ---------------- scatter: edgeOf[rankS], dstp[rankS] ----------------
__global__ void scatter_kernel(const int* __restrict__ src, const int* __restrict__ dst,
                               const int* __restrict__ rowptr, int* __restrict__ fill,
                               int* __restrict__ edgeOf, int* __restrict__ dstp) {
    int e = blockIdx.x * 256 + threadIdx.x;
    if (e < N_EDGES) {
        int s = src[e];
        int r = rowptr[s] + atomicAdd(&fill[s], 1);
        edgeOf[r] = e;
        dstp[r] = dst[e];
    }
}

// ---------------- x0 = relu(h @ lin0_w + b); f32 + xh frag mirror + fused xb2 ----------------
__global__ void lin0_kernel(const float* __restrict__ h, const float* __restrict__ w,
                            const float* __restrict__ b, const float* __restrict__ b2,
                            float* __restrict__ x, unsigned short* __restrict__ xh,
                            float* __restrict__ xb2) {
    int wv = threadIdx.x >> 6, l = threadIdx.x & 63;
    int n = blockIdx.x * 4 + wv;
    float h0 = h[n * HID + l];
    float h1 = h[n * HID + 64 + l];
    float acc = b[l];
#pragma unroll
    for (int i = 0; i < 64; ++i) {
        acc += __shfl(h0, i) * w[i * NF + l];
        acc += __shfl(h1, i) * w[(64 + i) * NF + l];
    }
    float v = fmaxf(acc, 0.0f);
    x[n * NF + l] = v;
    xh[fidx64(n, l)] = f2b(v);
    float xb = 0.0f;
#pragma unroll
    for (int i = 0; i < 64; ++i) xb += __shfl(v, i) * b2[i * 64 + l];
    xb2[n * NF + l] = xb;
}

// ---------------- eaperm: ea rows -> rank order, single-bf16, fragment-major (K pad 128) ----------------
__global__ void eaperm_kernel(const float* __restrict__ ea, const int* __restrict__ edgeOf,
                              unsigned short* __restrict__ eah) {
    int t = threadIdx.x;
    int r15 = t & 15, ksl = t >> 4;
    int ks = ksl >> 2, lk = ksl & 3;
    long rank = (long)blockIdx.x * 16 + r15;
    long e = edgeOf[rank];
    int c0 = ks * 32 + lk * 8;
    unsigned int uh[4];
#pragma unroll
    for (int p = 0; p < 4; ++p) {
        float v0 = (c0 + 2 * p < NG) ? ea[e * NG + c0 + 2 * p] : 0.0f;
        float v1 = (c0 + 2 * p + 1 < NG) ? ea[e * NG + c0 + 2 * p + 1] : 0.0f;
        uh[p] = ((unsigned int)f2b(v1) << 16) | f2b(v0);
    }
    long idx = (long)blockIdx.x * 2048 + ks * 512 + (lk * 16 + r15) * 8;
    *(uint4*)(eah + idx) = make_uint4(uh[0], uh[1], uh[2], uh[3]);
}

// ---------------- merged weight permute: w1 single (first 16384 ids) + w2 single ----------------
__global__ void wpt_kernel(const float* __restrict__ w1, const float* __restrict__ w2,
                           unsigned short* __restrict__ w1h, unsigned short* __restrict__ w2h) {
    int id = blockIdx.x * 256 + threadIdx.x;
    if (id < HID * HID) {  // w1: k = id&127, c = id>>7
        int k = id & 127, c = id >> 7;
        float v = (k < NG) ? w1[k * HID + c] : 0.0f;
        w1h[fidx128(c, k)] = f2b(v);
    } else {
        int id2 = id - HID * HID;  // id2 = j*64 + i
        int i = id2 & 63, j = id2 >> 6;
        int o = j >> 7, k = j & 127;  // j = o*128 + k
        w2h[fidx64(j, i)] = f2b(w2[k * NIO + i * 64 + o]);
    }
}

// ---------------- hgemm: hidp = relu(eap @ w1 + b1), single-pass bf16 ----------------
__launch_bounds__(256)
__global__ void hgemm_kernel(const unsigned short* __restrict__ eah,
                             const unsigned short* __restrict__ w1h,
                             const float* __restrict__ b1, unsigned short* __restrict__ hidp) {
    __shared__ float stg[4][1056];
    const int tid = threadIdx.x, wv = tid >> 6, l = tid & 63;
    const long grow = (long)blockIdx.x * 128;
    const int wr = (wv >> 1) * 64, wc = (wv & 1) * 64;
    const long apan0 = (grow >> 4) + (wr >> 4);
    const long bpan0 = (wc >> 4);

    f32x4 acc[4][4] = {};
#pragma unroll
    for (int ks = 0; ks < 4; ++ks) {
        bf16x8 a[4], b[4];
#pragma unroll
        for (int m = 0; m < 4; ++m)
            a[m] = *(const bf16x8*)(eah + (apan0 + m) * 2048 + ks * 512 + (long)l * 8);
#pragma unroll
        for (int n = 0; n < 4; ++n)
            b[n] = *(const bf16x8*)(w1h + (bpan0 + n) * 2048 + ks * 512 + (long)l * 8);
#pragma unroll
        for (int m = 0; m < 4; ++m)
#pragma unroll
            for (int n = 0; n < 4; ++n)
                acc[m][n] = __builtin_amdgcn_mfma_f32_16x16x32_bf16(a[m], b[n], acc[m][n], 0, 0, 0);
    }

    float* s = stg[wv];
    int r8 = l >> 3, cg = l & 7;
#pragma unroll
    for (int m = 0; m < 4; ++m) {
#pragma unroll
        for (int n = 0; n < 4; ++n)
#pragma unroll
            for (int q = 0; q < 4; ++q)
                s[((l >> 4) * 4 + q) * 66 + n * 16 + (l & 15)] = acc[m][n][q];
#pragma unroll
        for (int it = 0; it < 2; ++it) {
            int row = it * 8 + r8;
            const float* sr = s + row * 66 + cg * 8;
            int colbase = wc + cg * 8;
            unsigned int u[4];
#pragma unroll
            for (int p = 0; p < 4; ++p) {
                float f0 = fmaxf(sr[2 * p] + b1[colbase + 2 * p], 0.0f);
                float f1 = fmaxf(sr[2 * p + 1] + b1[colbase + 2 * p + 1], 0.0f);
                u[p] = ((unsigned int)f2b(f1) << 16) | f2b(f0);
            }
            long R = grow + wr + m * 16 + row;
            *(uint4*)(hidp + R * HID + colbase) = make_uint4(u[0], u[1], u[2], u[3]);
        }
    }
}

// ---------------- ygemm: single-pass bf16 (xh, w2h) ----------------
__launch_bounds__(256)
__global__ void ygemm_kernel(const unsigned short* __restrict__ xh,
                             const unsigned short* __restrict__ wh,
                             unsigned short* __restrict__ y, int n0) {
    __shared__ float stg[4][1056];
    const int tid = threadIdx.x, wv = tid >> 6, l = tid & 63;
    const int grow = blockIdx.x * 128;
    const int col0 = blockIdx.y * 128;
    const int wr = (wv >> 1) * 64, wc = (wv & 1) * 64;
    const long apan0 = ((n0 + grow + wr) >> 4);
    const long bpan0 = ((col0 + wc) >> 4);

    f32x4 acc[4][4] = {};
#pragma unroll
    for (int ks = 0; ks < 2; ++ks) {
        bf16x8 a[4], b[4];
#pragma unroll
        for (int m = 0; m < 4; ++m)
            a[m] = *(const bf16x8*)(xh + (apan0 + m) * 1024 + ks * 512 + (long)l * 8);
#pragma unroll
        for (int n = 0; n < 4; ++n)
            b[n] = *(const bf16x8*)(wh + (bpan0 + n) * 1024 + ks * 512 + (long)l * 8);
#pragma unroll
        for (int m = 0; m < 4; ++m)
#pragma unroll
            for (int n = 0; n < 4; ++n)
                acc[m][n] = __builtin_amdgcn_mfma_f32_16x16x32_bf16(a[m], b[n], acc[m][n], 0, 0, 0);
    }

    float* s = stg[wv];
    int r8 = l >> 3, cg = l & 7;
#pragma unroll
    for (int m = 0; m < 4; ++m) {
#pragma unroll
        for (int n = 0; n < 4; ++n)
#pragma unroll
            for (int q = 0; q < 4; ++q)
                s[((l >> 4) * 4 + q) * 66 + n * 16 + (l & 15)] = acc[m][n][q];
#pragma unroll
        for (int it = 0; it < 2; ++it) {
            int row = it * 8 + r8;
            const float* sr = s + row * 66 + cg * 8;
            unsigned int u[4];
#pragma unroll
            for (int p = 0; p < 4; ++p)
                u[p] = ((unsigned int)f2b(sr[2 * p + 1]) << 16) | f2b(sr[2 * p]);
            long R = grow + wr + m * 16 + row;
            *(uint4*)(y + R * NJ + col0 + wc + cg * 8) = make_uint4(u[0], u[1], u[2], u[3]);
        }
    }
}

// ---------------- per-node MFMA matvec: atomic scatter into agg ----------------
__global__ void matvec_mfma_kernel(const unsigned short* __restrict__ y,
                                   const unsigned short* __restrict__ hidp,
                                   const int* __restrict__ rowptr, const int* __restrict__ dstp,
                                   const float* __restrict__ xb2, float* __restrict__ agg,
                                   int n0) {
    int wv = threadIdx.x >> 6, l = threadIdx.x & 63;
    int s = n0 + blockIdx.x;
    int r0 = rowptr[s], r1 = rowptr[s + 1];
    if (r0 == r1) return;
    int co = wv * 16;
    int lc = l & 15, lk = l >> 4;

    const unsigned short* Ys = y + (long)(s - n0) * NJ + (co + lc) * HID;
    bf16x8 b[4];
#pragma unroll
    for (int ks = 0; ks < 4; ++ks) b[ks] = *(const bf16x8*)(Ys + ks * 32 + lk * 8);
    float xb2v = xb2[(long)s * NF + co + lc];

    for (int mt = r0; mt < r1; mt += 16) {
        const unsigned short* Hs = hidp + (long)(mt + lc) * HID + lk * 8;
        f32x4 acc = {};
#pragma unroll
        for (int ks = 0; ks < 4; ++ks) {
            bf16x8 a = *(const bf16x8*)(Hs + ks * 32);  // rows beyond r1: pad garbage, discarded
            acc = __builtin_amdgcn_mfma_f32_16x16x32_bf16(a, b[ks], acc, 0, 0, 0);
        }
#pragma unroll
        for (int q = 0; q < 4; ++q) {
            int rank = mt + lk * 4 + q;
            if (rank < r1) {
                int dd = dstp[rank];
                atomicAdd(&agg[(long)dd * NF + co + lc], acc[q] + xb2v);
            }
        }
    }
}

// ---------------- combine: agg*inv_deg + x @ root_w + conv_b (+ conv0: xh mirror & next xb2) ----------------
__global__ void combine_kernel(const float* __restrict__ x, const float* __restrict__ agg,
                               const float* __restrict__ invd, const float* __restrict__ rw,
                               const float* __restrict__ cb, const float* __restrict__ b2,
                               float* __restrict__ xo, unsigned short* __restrict__ xh,
                               float* __restrict__ xb2) {
    int wv = threadIdx.x >> 6, l = threadIdx.x & 63;
    int n = blockIdx.x * 4 + wv;
    float xv = x[n * NF + l];
    float acc = cb[l];
#pragma unroll
    for (int i = 0; i < 64; ++i) acc += __shfl(xv, i) * rw[i * NF + l];
    float v = agg[n * NF + l] * invd[n] + acc;
    xo[n * NF + l] = v;
    if (xh) {
        xh[fidx64(n, l)] = f2b(v);
        float xb = 0.0f;
#pragma unroll
        for (int i = 0; i < 64; ++i) xb += __shfl(v, i) * b2[i * 64 + l];
        xb2[n * NF + l] = xb;
    }
}

extern "C" void kernel_launch(void* const* d_in, const int* in_sizes, int n_in,
                              void* d_out, int out_size, void* d_ws, size_t ws_size,
                              hipStream_t stream) {
    const float* h = (const float*)d_in[0];
    const int* ei = (const int*)d_in[1];
    const float* ea = (const float*)d_in[3];
    const float* lin0_w = (const float*)d_in[5];
    const float* lin0_b = (const float*)d_in[6];
    const float* nn_w1 = (const float*)d_in[7];
    const float* nn_b1 = (const float*)d_in[8];
    const float* nn_w2 = (const float*)d_in[9];
    const float* nn_b2 = (const float*)d_in[10];
    const float* root_w = (const float*)d_in[11];
    const float* conv_b = (const float*)d_in[12];
    const int* srcIdx = ei;
    const int* dstIdx = ei + N_EDGES;

    // ---- tier selection: start at nc=2 so the y chunk (~84MB) stays LLC-resident ----
    const size_t eaBytes = (size_t)N_EDGES * HID * 2;  // eah (aliased with y region)
    const size_t fixed =
        (size_t)(N_EDGES + 16) * HID * 2 +  // hidp
        (size_t)NJ * NF * 2 +               // w2h
        (size_t)HID * HID * 2 +             // w1h
        (size_t)M_PAD * NF * 2 +            // xh mirror
        (size_t)N_NODES * NF * 4 * 4 +      // xA, xB, agg, xb2
        3 * 40192 +                         // deg | cnt | fill block
        (size_t)N_NODES * 4 +               // invd
        (size_t)(N_NODES + 1) * 4 +         // rowptr
        (size_t)N_EDGES * 4 * 2 +           // edgeOf, dstp
        32768;
    int nc = 0, CSn = 0;
    size_t region_bytes = 0;
    for (int c = 2; c <= 16; c *= 2) {
        int csn = (((N_NODES + c - 1) / c) + 127) & ~127;
        size_t rb = (size_t)csn * NJ * 2;
        if (rb < eaBytes) rb = eaBytes;
        if (fixed + rb <= ws_size) { nc = c; CSn = csn; region_bytes = rb; break; }
    }
    if (nc == 0) {
        hipMemsetAsync(d_out, 0, (size_t)out_size * 4, stream);
        return;
    }

    char* ws = (char*)d_ws;
    size_t off = 0;
    auto alloc = [&](size_t bytes) {
        char* p = ws + off;
        off += (bytes + 255) & ~(size_t)255;
        return p;
    };
    unsigned short* region = (unsigned short*)alloc(region_bytes);
    unsigned short* y = region;
    unsigned short* eah = region;  // prep only (consumed by hgemm before first ygemm)
    unsigned short* hidp = (unsigned short*)alloc((size_t)(N_EDGES + 16) * HID * 2);
    unsigned short* w2h = (unsigned short*)alloc((size_t)NJ * NF * 2);
    unsigned short* w1h = (unsigned short*)alloc((size_t)HID * HID * 2);
    unsigned short* xh = (unsigned short*)alloc((size_t)M_PAD * NF * 2);
    float* xA = (float*)alloc((size_t)N_NODES * NF * 4);
    float* xB = (float*)alloc((size_t)N_NODES * NF * 4);
    float* agg = (float*)alloc((size_t)N_NODES * NF * 4);
    float* xb2 = (float*)alloc((size_t)N_NODES * NF * 4);
    char* degblk = alloc(3 * 40192);  // deg | cnt | fill (one memset)
    float* deg = (float*)degblk;
    int* cnt = (int*)(degblk + 40192);
    int* fill = (int*)(degblk + 2 * 40192);
    float* invd = (float*)alloc((size_t)N_NODES * 4);
    int* rowptr = (int*)alloc((size_t)(N_NODES + 1) * 4);
    int* edgeOf = (int*)alloc((size_t)N_EDGES * 4);
    int* dstp = (int*)alloc((size_t)N_EDGES * 4);

    // ---- prep: CSR by src + features + weights + hidden ----
    hipMemsetAsync(degblk, 0, 3 * 40192, stream);
    hist_kernel<<<(N_EDGES + 255) / 256, 256, 0, stream>>>(srcIdx, dstIdx, deg, cnt);
    scan_kernel<<<1, 256, 0, stream>>>(cnt, deg, rowptr, invd);
    scatter_kernel<<<(N_EDGES + 255) / 256, 256, 0, stream>>>(srcIdx, dstIdx, rowptr, fill, edgeOf, dstp);
    lin0_kernel<<<N_NODES / 4, 256, 0, stream>>>(h, lin0_w, lin0_b, nn_b2, xA, xh, xb2);
    eaperm_kernel<<<N_EDGES / 16, 256, 0, stream>>>(ea, edgeOf, eah);
    wpt_kernel<<<(HID * HID + NJ * NF) / 256, 256, 0, stream>>>(nn_w1, nn_w2, w1h, w2h);
    hgemm_kernel<<<N_EDGES / 128, 256, 0, stream>>>(eah, w1h, nn_b1, hidp);  // consumes ea region

    // ---- two conv applications (shared weights) ----
    for (int conv = 0; conv < 2; ++conv) {
        const float* xin = conv ? xB : xA;
        float* xout = conv ? (float*)d_out : xB;
        unsigned short* mh = conv ? nullptr : xh;

        hipMemsetAsync(agg, 0, (size_t)N_NODES * NF * 4, stream);
        for (int c = 0; c < nc; ++c) {
            int n0 = c * CSn;
            int n1 = n0 + CSn; if (n1 > N_NODES) n1 = N_NODES;
            if (n0 >= N_NODES) break;
            int gx = (n1 - n0 + 127) / 128;
            ygemm_kernel<<<dim3(gx, NJ / 128), 256, 0, stream>>>(xh, w2h, y, n0);
            matvec_mfma_kernel<<<n1 - n0, 256, 0, stream>>>(y, hidp, rowptr, dstp, xb2, agg, n0);
        }
        combine_kernel<<<N_NODES / 4, 256, 0, stream>>>(xin, agg, invd, root_w, conv_b, nn_b2,
                                                        xout, mh, xb2);
    }
}